// Round 8
// baseline (701.033 us; speedup 1.0000x reference)
//
#include <hip/hip_runtime.h>

typedef __bf16 bf16;
typedef bf16 bf16x8 __attribute__((ext_vector_type(8)));
typedef bf16 bf16x4 __attribute__((ext_vector_type(4)));
typedef float f32x4 __attribute__((ext_vector_type(4)));

#define B_ 4
#define N1 4096
#define N2 256
#define DIM 1024
#define HEADS 16
#define DH 64
#define INNER 1024
#define ASPLIT 4
#define KEYS_PER_SPLIT (N1 / ASPLIT)      // 1024
#define SPLIT_ELEMS (4 * 16 * 256 * 64)   // elems per split partial (bf16)
#define ROWS_TOTAL (4 * HEADS * N2)       // 16384 rows per split

// async global->LDS, 16B per lane; LDS dest = wave-uniform base + lane*16
typedef __attribute__((address_space(1))) const void gvoid_t;
typedef __attribute__((address_space(3))) void lvoid_t;
__device__ __forceinline__ void async16(const void* g, void* l) {
  __builtin_amdgcn_global_load_lds((gvoid_t*)g, (lvoid_t*)l, 16, 0, 0);
}

// ---------------------------------------------------------------------------
// prep: fused weight transposes + both LayerNorms in one launch. (unchanged)
// ---------------------------------------------------------------------------
__global__ __launch_bounds__(256) void prep(
    const float* __restrict__ Wq, const float* __restrict__ Wkv,
    const float* __restrict__ Wout, bf16* __restrict__ WqT,
    bf16* __restrict__ WkvT, bf16* __restrict__ WoutT,
    const float* __restrict__ x, const float* __restrict__ latents,
    const float* __restrict__ ln1w, const float* __restrict__ ln1b,
    const float* __restrict__ ln2w, const float* __restrict__ ln2b,
    bf16* __restrict__ xn, bf16* __restrict__ lnl) {
  __shared__ float tile[32][33];
  int t = blockIdx.x;
  if (t < 4096) {  // ---- transpose path ----
    const float* src;
    bf16* dst;
    int N;
    if (t < 1024) { src = Wq; dst = WqT; N = 1024; }
    else if (t < 3072) { t -= 1024; src = Wkv; dst = WkvT; N = 2048; }
    else { t -= 3072; src = Wout; dst = WoutT; N = 1024; }
    int ntiles = N >> 5;
    int n0 = (t % ntiles) * 32, k0 = (t / ntiles) * 32;
    int xx = threadIdx.x & 31, yy = threadIdx.x >> 5;
    for (int j = 0; j < 4; j++)
      tile[yy + 8 * j][xx] = src[(size_t)(k0 + yy + 8 * j) * N + n0 + xx];
    __syncthreads();
    for (int j = 0; j < 4; j++)
      dst[(size_t)(n0 + yy + 8 * j) * 1024 + k0 + xx] = (bf16)tile[xx][yy + 8 * j];
    return;
  }
  // ---- LN path ----
  int wv = threadIdx.x >> 6, lane = threadIdx.x & 63;
  int grow = (t - 4096) * 4 + wv;
  const float *src, *w, *bb;
  bf16* dst;
  int row;
  if (grow < 16384) { src = x; w = ln1w; bb = ln1b; dst = xn; row = grow; }
  else { src = latents; w = ln2w; bb = ln2b; dst = lnl; row = grow - 16384; }
  const float4* p = (const float4*)(src + (size_t)row * DIM);
  float4 v[4];
  for (int j = 0; j < 4; j++) v[j] = p[j * 64 + lane];
  float s = 0.f, sq = 0.f;
  for (int j = 0; j < 4; j++) {
    s += v[j].x + v[j].y + v[j].z + v[j].w;
    sq += v[j].x * v[j].x + v[j].y * v[j].y + v[j].z * v[j].z + v[j].w * v[j].w;
  }
  for (int off = 32; off; off >>= 1) {
    s += __shfl_xor(s, off, 64);
    sq += __shfl_xor(sq, off, 64);
  }
  float mu = s * (1.0f / DIM);
  float var = sq * (1.0f / DIM) - mu * mu;
  float r = rsqrtf(var + 1e-5f);
  for (int j = 0; j < 4; j++) {
    float4 wv4 = ((const float4*)w)[j * 64 + lane];
    float4 bv4 = ((const float4*)bb)[j * 64 + lane];
    bf16x4 o;
    o[0] = (bf16)((v[j].x - mu) * r * wv4.x + bv4.x);
    o[1] = (bf16)((v[j].y - mu) * r * wv4.y + bv4.y);
    o[2] = (bf16)((v[j].z - mu) * r * wv4.z + bv4.z);
    o[3] = (bf16)((v[j].w - mu) * r * wv4.w + bv4.w);
    *(bf16x4*)(dst + (size_t)row * DIM + (j * 64 + lane) * 4) = o;
  }
}

// ---------------------------------------------------------------------------
// Big GEMM (kv) + fused q-projection.
// ROUND-8: kv pipeline moves from {2 buf x BK=64, 128 KiB LDS, 1 block/CU}
// to {2 buf x BK=32, 64 KiB LDS, 2 blocks/CU}. Per-barrier pattern is
// unchanged (8 MFMA/barrier, counted vmcnt(4), stage issued >=2 barriers +
// one MFMA region after the last read of the buffer it overwrites). The win
// is cross-block overlap: a co-resident block's MFMAs fill this block's
// read-burst/barrier stalls (m97 mechanism). Dynamic LDS = 69632 B
// (epilogue transpose needs 8 x 8704); 2 x 69.6 KB <= 160 KB.
// Blocks [512,768): q-projection tail (r7, unchanged).
// ---------------------------------------------------------------------------
__device__ __forceinline__ int swz_off(int row, int cb) {
  int line = row >> 1;
  return (line << 7) + (((((row & 1) << 2) | cb) ^ (line & 7)) << 4);
}

__global__ __launch_bounds__(512, 4) void gemm_kv256(
    const bf16* __restrict__ A, const bf16* __restrict__ Bt,
    bf16* __restrict__ Cout, bf16* __restrict__ Cout2,
    const bf16* __restrict__ Aq, const bf16* __restrict__ Bq,
    bf16* __restrict__ qout, const float* __restrict__ shiftp,
    const float* __restrict__ scalep) {
  extern __shared__ char smem[];
  int tid = threadIdx.x;
  int lane = tid & 63, wv = tid >> 6;
  int lr = lane & 15, quad = lane >> 4;
  int bid = blockIdx.x;

  if (bid >= 512) {
    // ---- fused q-projection: 64x64 tile, 8 waves (16x32 out each),
    // 3-buffer counted rotation (1 async16/thread/matrix -> vmcnt(2)) ----
    int q2 = bid - 512;  // 0..255
    int m0q = (q2 >> 4) * 64, n0q = (q2 & 15) * 64;
    int wrq = wv >> 1, wcq = wv & 1;
    int srow = tid >> 3;
    int scb = (tid & 7) ^ (srow & 7);
    size_t ga = (size_t)(m0q + srow) * 1024 + scb * 8;
    size_t gb = (size_t)(n0q + srow) * 1024 + scb * 8;
    int ldsW = wv * 1024;  // wave-uniform byte base (lane*16 implicit)
    auto stq = [&](int step, int buf) {
      int kt = step * 64;
      async16(&Aq[ga + kt], smem + buf * 8192 + ldsW);
      async16(&Bq[gb + kt], smem + 24576 + buf * 8192 + ldsW);
    };
    f32x4 accq[2] = {};
    stq(0, 0);
    stq(1, 1);
    asm volatile("s_waitcnt vmcnt(2)" ::: "memory");
    __builtin_amdgcn_s_barrier();
#pragma unroll 1
    for (int s = 0; s < 16; s++) {
      int cur = s % 3;
      int nxt = (s + 2 < 16) ? s + 2 : 15;  // tail: dead restage
      stq(nxt, (s + 2) % 3);
      const bf16* Ab = (const bf16*)(smem + cur * 8192);
      const bf16* Bb = (const bf16*)(smem + 24576 + cur * 8192);
      for (int kk = 0; kk < 2; kk++) {
        int arow = wrq * 16 + lr;
        bf16x8 afq =
            *(const bf16x8*)&Ab[arow * 64 + ((4 * kk + quad) ^ (arow & 7)) * 8];
        for (int in = 0; in < 2; in++) {
          int brow = wcq * 32 + in * 16 + lr;
          bf16x8 bfq =
              *(const bf16x8*)&Bb[brow * 64 + ((4 * kk + quad) ^ (brow & 7)) * 8];
          accq[in] = __builtin_amdgcn_mfma_f32_16x16x32_bf16(afq, bfq, accq[in],
                                                             0, 0, 0);
        }
      }
      asm volatile("s_waitcnt vmcnt(2)" ::: "memory");
      __builtin_amdgcn_s_barrier();
    }
    // epilogue: AdaLN modulation * attn_scale * log2e, bf16 store
    for (int in = 0; in < 2; in++) {
      int col = n0q + wcq * 32 + in * 16 + lr;
      int hh = col >> 6;
      for (int r = 0; r < 4; r++) {
        int row = m0q + wrq * 16 + quad * 4 + r;
        int bb = row >> 8;
        float sc = scalep[bb * 16 + hh], sh = shiftp[bb * 16 + hh];
        qout[(size_t)row * 1024 + col] =
            (bf16)((accq[in][r] * (1.0f + sc) + sh) * 0.18033688011112042f);
      }
    }
    return;
  }

  // ---- kv path: BK=32, 2 buffers, 64 KiB pipeline LDS ----
  int wr = wv >> 2, wc = wv & 3;
  int mt = (bid & 7) * 8 + ((bid >> 3) >> 3), nt = (bid >> 3) & 7;
  int m0 = mt * 256, n0 = nt * 256;

  // fragment byte-offsets within a 256x32 k-step tile (16 KiB)
  int offA[8], offB[4];
#pragma unroll
  for (int im = 0; im < 8; im++) offA[im] = swz_off(wr * 128 + im * 16 + lr, quad);
#pragma unroll
  for (int in = 0; in < 4; in++) offB[in] = swz_off(wc * 64 + in * 16 + lr, quad);

  // staging: unit u = s*512+tid holds logical (row, cb) of the k-step tile
  size_t gA[2], gB[2];
#pragma unroll
  for (int s = 0; s < 2; s++) {
    int u = s * 512 + tid;
    int line = u >> 3, inner = (u & 7) ^ (line & 7);
    int row = line * 2 + (inner >> 2), cb = inner & 3;
    gA[s] = (size_t)(m0 + row) * 1024 + cb * 8;
    gB[s] = (size_t)(n0 + row) * 1024 + cb * 8;
  }
  int ldsS0 = wv * 1024, ldsS1 = 8192 + wv * 1024;  // wave-uniform LDS dests

  // stage k-step w into buffer buf: A at buf*16K, B at 32K + buf*16K
  auto stAB = [&](int w, int buf) {
    int k0 = w * 32;
    char* ba = smem + buf * 16384;
    char* bb = smem + 32768 + buf * 16384;
    async16(&A[gA[0] + k0], ba + ldsS0);
    async16(&A[gA[1] + k0], ba + ldsS1);
    async16(&Bt[gB[0] + k0], bb + ldsS0);
    async16(&Bt[gB[1] + k0], bb + ldsS1);
  };

  f32x4 acc[8][4] = {};

  // prologue: step0 -> buf0, step1 -> buf1; wait step0 (4 newest in flight)
  stAB(0, 0);
  stAB(1, 1);
  asm volatile("s_waitcnt vmcnt(4)" ::: "memory");
  __builtin_amdgcn_s_barrier();

#pragma unroll 1
  for (int s = 0; s < 32; s++) {
    int buf = s & 1;
    const char* A0 = smem + buf * 16384;
    const char* B0 = smem + 32768 + buf * 16384;
    int w2 = (s + 2 < 32) ? s + 2 : 31;  // tail: dead restage into drained buf
    bf16x8 af[4], bfr[4];
    // ---- P1: mh0 ----
#pragma unroll
    for (int in = 0; in < 4; in++) bfr[in] = *(const bf16x8*)(B0 + offB[in]);
#pragma unroll
    for (int im = 0; im < 4; im++) af[im] = *(const bf16x8*)(A0 + offA[im]);
    __builtin_amdgcn_s_barrier();
    __builtin_amdgcn_s_setprio(1);
#pragma unroll
    for (int im = 0; im < 4; im++)
#pragma unroll
      for (int in = 0; in < 4; in++)
        acc[im][in] = __builtin_amdgcn_mfma_f32_16x16x32_bf16(
            af[im], bfr[in], acc[im][in], 0, 0, 0);
    __builtin_amdgcn_s_setprio(0);
    __builtin_amdgcn_s_barrier();
    // ---- P2: mh1 ----
#pragma unroll
    for (int im = 0; im < 4; im++) af[im] = *(const bf16x8*)(A0 + offA[4 + im]);
    __builtin_amdgcn_s_barrier();  // all waves' reads of buf are issued
    __builtin_amdgcn_s_setprio(1);
#pragma unroll
    for (int im = 0; im < 4; im++)
#pragma unroll
      for (int in = 0; in < 4; in++)
        acc[4 + im][in] = __builtin_amdgcn_mfma_f32_16x16x32_bf16(
            af[im], bfr[in], acc[4 + im][in], 0, 0, 0);
    __builtin_amdgcn_s_setprio(0);
    // stage s+2 -> buf (the one just fully consumed): issued one full MFMA
    // region + 2 barriers after the last ds_read of this buffer.
    stAB(w2, buf);
    // counted guard: stage(s+1) proven landed (only stage(s+2)'s 4 remain)
    asm volatile("s_waitcnt vmcnt(4)" ::: "memory");
    __builtin_amdgcn_s_barrier();
  }

  // drain remaining in-flight stages before reusing LDS in the epilogue
  asm volatile("s_waitcnt vmcnt(0)" ::: "memory");
  __builtin_amdgcn_s_barrier();

  if (n0 < 1024) {
    // K half: direct bf16 stores (L2 combines the 16-lane segments)
#pragma unroll
    for (int im = 0; im < 8; im++)
#pragma unroll
      for (int in = 0; in < 4; in++) {
        int col = n0 + wc * 64 + in * 16 + lr;
#pragma unroll
        for (int r = 0; r < 4; r++) {
          int row = m0 + wr * 128 + im * 16 + quad * 4 + r;
          Cout[(size_t)row * 1024 + col] = (bf16)acc[im][in][r];
        }
      }
    return;
  }
  // V half: per-wave LDS transpose (own 8704B region), b128 stores along key
  int b2 = m0 >> 12;
  int key0 = (m0 & 4095) + wr * 128;
  int gc0 = (n0 - 1024) + wc * 64;
  bf16* Tw = (bf16*)(smem + wv * 8704);  // [32 cols][136 keys pitch]
  for (int pass = 0; pass < 2; pass++) {
#pragma unroll
    for (int ii = 0; ii < 2; ii++) {
      int in = pass * 2 + ii;
      int cl = ii * 16 + lr;
#pragma unroll
      for (int im = 0; im < 8; im++) {
        bf16x4 pk;
#pragma unroll
        for (int r = 0; r < 4; r++) pk[r] = (bf16)acc[im][in][r];
        *(bf16x4*)&Tw[cl * 136 + im * 16 + quad * 4] = pk;
      }
    }
    asm volatile("s_waitcnt lgkmcnt(0)" ::: "memory");
#pragma unroll
    for (int j = 0; j < 8; j++) {
      int idx = j * 64 + lane;
      int cl = idx >> 4, k8 = idx & 15;
      uint4 val = *(const uint4*)&Tw[cl * 136 + k8 * 8];
      *(uint4*)&Cout2[((size_t)(b2 * 1024 + gc0 + pass * 32 + cl)) * 4096 +
                      key0 + k8 * 8] = val;
    }
    asm volatile("s_waitcnt lgkmcnt(0)" ::: "memory");
  }
}

// ---------------------------------------------------------------------------
// Small GEMM: 64x64 tile, BK=64, 3-buffer rotation with counted vmcnt.
// (round-3 version; used only for the output projection)
// ---------------------------------------------------------------------------
template <int MODE>
__global__ __launch_bounds__(256) void gemm64(
    const bf16* __restrict__ A, const bf16* __restrict__ Bt,
    void* __restrict__ Cout, int K, int N,
    const float* __restrict__ shiftp, const float* __restrict__ scalep) {
  __shared__ __align__(16) bf16 As[3][64 * 64];
  __shared__ __align__(16) bf16 Bs[3][64 * 64];
  int tid = threadIdx.x;
  int lane = tid & 63, wv = tid >> 6;
  int wr = wv >> 1, wc = wv & 1;
  int quad = lane >> 4, lr = lane & 15;
  int m0 = blockIdx.y * 64, n0 = blockIdx.x * 64;
  f32x4 acc[2][2] = {};

  auto stage = [&](int step, int buf) {
    int kt = step * 64;
    for (int j = 0; j < 2; j++) {
      int idx0 = j * 256 + wv * 64;
      int row = (idx0 >> 3) + (lane >> 3);
      int cb = (lane & 7) ^ (row & 7);
      async16(&A[(size_t)(m0 + row) * K + kt + cb * 8], &As[buf][idx0 * 8]);
      async16(&Bt[(size_t)(n0 + row) * K + kt + cb * 8], &Bs[buf][idx0 * 8]);
    }
  };

  int nsteps = K >> 6;  // 16
  stage(0, 0);
  stage(1, 1);
  asm volatile("s_waitcnt vmcnt(4)" ::: "memory");
  __builtin_amdgcn_s_barrier();

#pragma unroll 1
  for (int s = 0; s < nsteps; s++) {
    int cur = s % 3;
    int nxt = (s + 2 < nsteps) ? s + 2 : nsteps - 1;  // tail: dead restage
    stage(nxt, (s + 2) % 3);
    for (int kk = 0; kk < 2; kk++) {
      bf16x8 af[2], bfr[2];
      for (int im = 0; im < 2; im++) {
        int row = wr * 32 + im * 16 + lr;
        af[im] =
            *(const bf16x8*)&As[cur][row * 64 + ((quad + 4 * kk) ^ (row & 7)) * 8];
      }
      for (int in = 0; in < 2; in++) {
        int row = wc * 32 + in * 16 + lr;
        bfr[in] =
            *(const bf16x8*)&Bs[cur][row * 64 + ((quad + 4 * kk) ^ (row & 7)) * 8];
      }
      for (int im = 0; im < 2; im++)
        for (int in = 0; in < 2; in++)
          acc[im][in] = __builtin_amdgcn_mfma_f32_16x16x32_bf16(
              af[im], bfr[in], acc[im][in], 0, 0, 0);
    }
    asm volatile("s_waitcnt vmcnt(4)" ::: "memory");
    __builtin_amdgcn_s_barrier();
  }

  for (int im = 0; im < 2; im++)
    for (int in = 0; in < 2; in++) {
      int col = n0 + wc * 32 + in * 16 + lr;
      for (int r = 0; r < 4; r++) {
        int row = m0 + wr * 32 + im * 16 + quad * 4 + r;
        float v = acc[im][in][r];
        if (MODE == 1) {
          int bb = row >> 8, hh = col >> 6;
          float sc = scalep[bb * 16 + hh], sh = shiftp[bb * 16 + hh];
          ((bf16*)Cout)[(size_t)row * N + col] =
              (bf16)((v * (1.0f + sc) + sh) * 0.18033688011112042f);
        } else {
          ((float*)Cout)[(size_t)row * N + col] = v;
        }
      }
    }
}

// ---------------------------------------------------------------------------
// Flash attention: merged q-tiles + exact defer-rescale. (round-5, kept)
// ---------------------------------------------------------------------------
__global__ __launch_bounds__(512) void attn_kernel(const bf16* __restrict__ q,
                                                   const bf16* __restrict__ kb,
                                                   const bf16* __restrict__ vt,
                                                   bf16* __restrict__ opb,
                                                   float* __restrict__ lseb) {
  int b = blockIdx.z, h = blockIdx.y;
  int sp = blockIdx.x;
  int tid = threadIdx.x, lane = tid & 63, wv = tid >> 6;
  int quad = lane >> 4, lr = lane & 15;
  __shared__ __align__(16) bf16 Ks[2][64 * 64];
  __shared__ __align__(16) bf16 Vs[2][64 * 64];   // [dh][key]
  __shared__ __align__(16) bf16 QP[256 * 64];     // 256 Q rows; P overlays own rows

  // stage all 256 Q rows (4 async16/thread, 8 waves x 8 rows per pass)
  const bf16* qg = q + (size_t)(b * N2) * INNER + h * DH;
  for (int j = 0; j < 4; j++) {
    int r0 = j * 64 + wv * 8;
    int r = r0 + (lane >> 3);
    async16(&qg[(size_t)r * INNER + ((lane & 7) ^ (r & 7)) * 8], &QP[r0 * 64]);
  }
  __syncthreads();
  bf16x8 aQ[2][2];
  for (int g = 0; g < 2; g++) {
    int row = wv * 32 + g * 16 + lr;
    for (int kk = 0; kk < 2; kk++)
      aQ[g][kk] = *(const bf16x8*)&QP[row * 64 + ((quad + 4 * kk) ^ (row & 7)) * 8];
  }
  float m_s[2] = {-1e30f, -1e30f}, l_s[2] = {0.0f, 0.0f};
  f32x4 oacc[2][4] = {};

  const bf16* kg = kb + (size_t)(b * N1) * 1024 + h * DH;
  const bf16* vg = vt + (size_t)((b * HEADS + h) * DH) * N1;
  bf16* Ps = QP + wv * 2048;  // wave's own 32 Q rows (Q already in regs)

  auto stageKV = [&](int t, int buf) {
    int key0 = sp * KEYS_PER_SPLIT + t * 64;
    int r0 = wv * 8;                 // 8 waves x 8 rows = 64 rows in one pass
    int r = r0 + (lane >> 3);
    int cs = ((lane & 7) ^ (r & 7)) * 8;
    async16(&kg[(size_t)(key0 + r) * 1024 + cs], &Ks[buf][r0 * 64]);
    async16(&vg[(size_t)r * N1 + key0 + cs], &Vs[buf][r0 * 64]);
  };

  // prologue: tile 0 into buf 0
  stageKV(0, 0);
  asm volatile("s_waitcnt vmcnt(0)" ::: "memory");
  __builtin_amdgcn_s_barrier();

  for (int t = 0; t < KEYS_PER_SPLIT / 64; t++) {
    int cur = t & 1;
    // hoist K/V fragments once, reuse across both q-groups
    bf16x8 ak[2][4], bv[2][4];
    for (int kk = 0; kk < 2; kk++)
      for (int nt = 0; nt < 4; nt++) {
        int row = nt * 16 + lr;
        ak[kk][nt] =
            *(const bf16x8*)&Ks[cur][row * 64 + ((quad + 4 * kk) ^ (row & 7)) * 8];
        bv[kk][nt] =
            *(const bf16x8*)&Vs[cur][row * 64 + ((quad + 4 * kk) ^ (row & 7)) * 8];
      }
    if (t + 1 < KEYS_PER_SPLIT / 64) stageKV(t + 1, cur ^ 1);

    for (int g = 0; g < 2; g++) {
      f32x4 s[4] = {};
      for (int kk = 0; kk < 2; kk++)
        for (int nt = 0; nt < 4; nt++)
          s[nt] = __builtin_amdgcn_mfma_f32_16x16x32_bf16(ak[kk][nt], aQ[g][kk],
                                                          s[nt], 0, 0, 0);
      // per-lane softmax for query = lr (16 keys in regs, reduce across quads)
      float mx = s[0][0];
      for (int nt = 0; nt < 4; nt++)
        for (int r = 0; r < 4; r++) mx = fmaxf(mx, s[nt][r]);
      mx = fmaxf(mx, __shfl_xor(mx, 16, 64));
      mx = fmaxf(mx, __shfl_xor(mx, 32, 64));
      float mo = m_s[g];
      float mn = fmaxf(mo, mx);
      float al = exp2f(mo - mn);
      float p[4][4], sum = 0.0f;
      for (int nt = 0; nt < 4; nt++)
        for (int r = 0; r < 4; r++) {
          p[nt][r] = exp2f(s[nt][r] - mn);
          sum += p[nt][r];
        }
      sum += __shfl_xor(sum, 16, 64);
      sum += __shfl_xor(sum, 32, 64);
      l_s[g] = l_s[g] * al + sum;
      m_s[g] = mn;

      // packed P writes: P[query=lr][key=16nt+4quad+r]
      for (int nt = 0; nt < 4; nt++) {
        bf16x4 pk;
        for (int r = 0; r < 4; r++) pk[r] = (bf16)p[nt][r];
        *(bf16x4*)&Ps[lr * 64 + ((2 * nt + (quad >> 1)) ^ (lr & 7)) * 8 +
                      (quad & 1) * 4] = pk;
      }

      // rescale O accumulator only when some lane's max grew (al != 1.0);
      // otherwise al == 1.0 exactly and the rescale is a no-op.
      if (__any(mn > mo)) {
        for (int r = 0; r < 4; r++) {
          float a = __shfl(al, quad * 4 + r, 16);
          for (int in = 0; in < 4; in++) oacc[g][in][r] *= a;
        }
      }

      bf16x8 aP[2];
      for (int kk = 0; kk < 2; kk++)
        aP[kk] = *(const bf16x8*)&Ps[lr * 64 + ((4 * kk + quad) ^ (lr & 7)) * 8];
      for (int kk = 0; kk < 2; kk++)
        for (int in = 0; in < 4; in++)
          oacc[g][in] = __builtin_amdgcn_mfma_f32_16x16x32_bf16(
              aP[kk], bv[kk][in], oacc[g][in], 0, 0, 0);
    }
    // stage issued at tile start has landed (whole compute passed): free wait
    asm volatile("s_waitcnt vmcnt(0)" ::: "memory");
    __builtin_amdgcn_s_barrier();
  }

  // epilogue: normalized bf16 partials + lse
  bf16* ob = opb + (size_t)sp * SPLIT_ELEMS;
  size_t rbase = (size_t)(b * HEADS + h) * N2;
  for (int g = 0; g < 2; g++) {
    for (int r = 0; r < 4; r++) {
      float lrow = __shfl(l_s[g], quad * 4 + r, 16);
      float inv = 1.0f / lrow;
      int qq = wv * 32 + g * 16 + quad * 4 + r;
      for (int in = 0; in < 4; in++)
        ob[(rbase + qq) * 64 + in * 16 + lr] = (bf16)(oacc[g][in][r] * inv);
    }
    if (quad == 0) {
      int qq = wv * 32 + g * 16 + lr;
      lseb[(size_t)sp * ROWS_TOTAL + rbase + qq] = m_s[g] + __log2f(l_s[g]);
    }
  }
}

// ---------------------------------------------------------------------------
// Combine (round-5 fixed version, kept): one thread per 8-elem d-chunk.
// ---------------------------------------------------------------------------
__global__ __launch_bounds__(256) void combine_kernel(const bf16* __restrict__ opb,
                                                      const float* __restrict__ lseb,
                                                      bf16* __restrict__ out) {
  int gid = blockIdx.x * 256 + threadIdx.x;  // 131072 threads total
  int dc = (gid & 7) * 8;
  int rq = gid >> 3;  // (b*16+h)*256 + q, in [0, 16384)
  int qq = rq & 255, bh = rq >> 8;
  int h = bh & 15, b = bh >> 4;
  float ls[ASPLIT];
  for (int s = 0; s < ASPLIT; s++) ls[s] = lseb[(size_t)s * ROWS_TOTAL + rq];
  float M = fmaxf(fmaxf(ls[0], ls[1]), fmaxf(ls[2], ls[3]));
  float L = 0.0f, w[ASPLIT];
  for (int s = 0; s < ASPLIT; s++) {
    w[s] = exp2f(ls[s] - M);
    L += w[s];
  }
  float inv = 1.0f / L;
  float o[8] = {};
  for (int s = 0; s < ASPLIT; s++) {
    bf16x8 v = *(const bf16x8*)&opb[(size_t)s * SPLIT_ELEMS + (size_t)rq * 64 + dc];
    for (int j = 0; j < 8; j++) o[j] += w[s] * (float)v[j];
  }
  bf16x8 ov;
  for (int j = 0; j < 8; j++) ov[j] = (bf16)(o[j] * inv);
  *(bf16x8*)&out[((size_t)(b * N2 + qq)) * INNER + h * DH + dc] = ov;
}

// ---------------------------------------------------------------------------
extern "C" void kernel_launch(void* const* d_in, const int* in_sizes, int n_in,
                              void* d_out, int out_size, void* d_ws,
                              size_t ws_size, hipStream_t stream) {
  const float* x       = (const float*)d_in[0];
  const float* latents = (const float*)d_in[1];
  const float* shift   = (const float*)d_in[2];
  const float* scale   = (const float*)d_in[3];
  const float* ln1w    = (const float*)d_in[4];
  const float* ln1b    = (const float*)d_in[5];
  const float* ln2w    = (const float*)d_in[6];
  const float* ln2b    = (const float*)d_in[7];
  const float* Wq      = (const float*)d_in[8];
  const float* Wkv     = (const float*)d_in[9];
  const float* Wout    = (const float*)d_in[10];

  char* ws = (char*)d_ws;
  bf16*  xn    = (bf16*)(ws);                // 32MiB; dead after gemm_kv
  bf16*  opb   = (bf16*)(ws);                //   overlay: 4 bf16 splits
  bf16*  lnl   = (bf16*)(ws + 33554432);     // 2MB; dead after q gemm
  float* lseb  = (float*)(ws + 33554432);    //   overlay: lse 256KB
  bf16*  qb    = (bf16*)(ws + 35651584);     // 2MB
  bf16*  kb    = (bf16*)(ws + 37748736);     // 32MiB (K half)
  bf16*  vtb   = (bf16*)(ws + 104857600);    // 32MiB (V^T)
  bf16*  aob   = (bf16*)(ws + 138412032);    // 2MB
  bf16*  WqT   = (bf16*)(ws + 140509184);    // 2MB
  bf16*  WkvT  = (bf16*)(ws + 142606336);    // 4MB
  bf16*  WoutT = (bf16*)(ws + 146800640);    // 2MB

  static bool attr_done = false;
  if (!attr_done) {
    hipFuncSetAttribute(reinterpret_cast<const void*>(gemm_kv256),
                        hipFuncAttributeMaxDynamicSharedMemorySize, 69632);
    attr_done = true;
  }

  prep<<<8448, 256, 0, stream>>>(Wq, Wkv, Wout, WqT, WkvT, WoutT, x, latents,
                                 ln1w, ln1b, ln2w, ln2b, xn, lnl);
  gemm_kv256<<<dim3(768), dim3(512), 69632, stream>>>(
      xn, WkvT, kb, vtb, lnl, WqT, qb, shift, scale);
  attn_kernel<<<dim3(ASPLIT, 16, 4), 512, 0, stream>>>(qb, kb, vtb, opb,
                                                       lseb);
  combine_kernel<<<512, 256, 0, stream>>>(opb, lseb, aob);
  gemm64<2><<<dim3(16, 16), 256, 0, stream>>>(aob, WoutT, d_out, 1024, 1024,
                                              nullptr, nullptr);
}

// Round 9
// 255.411 us; speedup vs baseline: 2.7447x; 2.7447x over previous
//
#include <hip/hip_runtime.h>

typedef __bf16 bf16;
typedef bf16 bf16x8 __attribute__((ext_vector_type(8)));
typedef bf16 bf16x4 __attribute__((ext_vector_type(4)));
typedef float f32x4 __attribute__((ext_vector_type(4)));

#define B_ 4
#define N1 4096
#define N2 256
#define DIM 1024
#define HEADS 16
#define DH 64
#define INNER 1024
#define ASPLIT 4
#define KEYS_PER_SPLIT (N1 / ASPLIT)      // 1024
#define SPLIT_ELEMS (4 * 16 * 256 * 64)   // elems per split partial (bf16)
#define ROWS_TOTAL (4 * HEADS * N2)       // 16384 rows per split

// async global->LDS, 16B per lane; LDS dest = wave-uniform base + lane*16
typedef __attribute__((address_space(1))) const void gvoid_t;
typedef __attribute__((address_space(3))) void lvoid_t;
__device__ __forceinline__ void async16(const void* g, void* l) {
  __builtin_amdgcn_global_load_lds((gvoid_t*)g, (lvoid_t*)l, 16, 0, 0);
}

// ---------------------------------------------------------------------------
// prep: fused weight transposes + both LayerNorms in one launch. (unchanged)
// ---------------------------------------------------------------------------
__global__ __launch_bounds__(256) void prep(
    const float* __restrict__ Wq, const float* __restrict__ Wkv,
    const float* __restrict__ Wout, bf16* __restrict__ WqT,
    bf16* __restrict__ WkvT, bf16* __restrict__ WoutT,
    const float* __restrict__ x, const float* __restrict__ latents,
    const float* __restrict__ ln1w, const float* __restrict__ ln1b,
    const float* __restrict__ ln2w, const float* __restrict__ ln2b,
    bf16* __restrict__ xn, bf16* __restrict__ lnl) {
  __shared__ float tile[32][33];
  int t = blockIdx.x;
  if (t < 4096) {  // ---- transpose path ----
    const float* src;
    bf16* dst;
    int N;
    if (t < 1024) { src = Wq; dst = WqT; N = 1024; }
    else if (t < 3072) { t -= 1024; src = Wkv; dst = WkvT; N = 2048; }
    else { t -= 3072; src = Wout; dst = WoutT; N = 1024; }
    int ntiles = N >> 5;
    int n0 = (t % ntiles) * 32, k0 = (t / ntiles) * 32;
    int xx = threadIdx.x & 31, yy = threadIdx.x >> 5;
    for (int j = 0; j < 4; j++)
      tile[yy + 8 * j][xx] = src[(size_t)(k0 + yy + 8 * j) * N + n0 + xx];
    __syncthreads();
    for (int j = 0; j < 4; j++)
      dst[(size_t)(n0 + yy + 8 * j) * 1024 + k0 + xx] = (bf16)tile[xx][yy + 8 * j];
    return;
  }
  // ---- LN path ----
  int wv = threadIdx.x >> 6, lane = threadIdx.x & 63;
  int grow = (t - 4096) * 4 + wv;
  const float *src, *w, *bb;
  bf16* dst;
  int row;
  if (grow < 16384) { src = x; w = ln1w; bb = ln1b; dst = xn; row = grow; }
  else { src = latents; w = ln2w; bb = ln2b; dst = lnl; row = grow - 16384; }
  const float4* p = (const float4*)(src + (size_t)row * DIM);
  float4 v[4];
  for (int j = 0; j < 4; j++) v[j] = p[j * 64 + lane];
  float s = 0.f, sq = 0.f;
  for (int j = 0; j < 4; j++) {
    s += v[j].x + v[j].y + v[j].z + v[j].w;
    sq += v[j].x * v[j].x + v[j].y * v[j].y + v[j].z * v[j].z + v[j].w * v[j].w;
  }
  for (int off = 32; off; off >>= 1) {
    s += __shfl_xor(s, off, 64);
    sq += __shfl_xor(sq, off, 64);
  }
  float mu = s * (1.0f / DIM);
  float var = sq * (1.0f / DIM) - mu * mu;
  float r = rsqrtf(var + 1e-5f);
  for (int j = 0; j < 4; j++) {
    float4 wv4 = ((const float4*)w)[j * 64 + lane];
    float4 bv4 = ((const float4*)bb)[j * 64 + lane];
    bf16x4 o;
    o[0] = (bf16)((v[j].x - mu) * r * wv4.x + bv4.x);
    o[1] = (bf16)((v[j].y - mu) * r * wv4.y + bv4.y);
    o[2] = (bf16)((v[j].z - mu) * r * wv4.z + bv4.z);
    o[3] = (bf16)((v[j].w - mu) * r * wv4.w + bv4.w);
    *(bf16x4*)(dst + (size_t)row * DIM + (j * 64 + lane) * 4) = o;
  }
}

// ---------------------------------------------------------------------------
// Big GEMM (kv) + fused q-projection. Blocks [0,512): verified r4 256x256
// kv schedule (BK=64, 128 KiB LDS, 2 waves/SIMD — the 128-AGPR accumulator
// binds occupancy to 1 block/CU; round-8's 4-waves/SIMD attempt spilled).
// Blocks [512,768): q = lnl @ WqT^T with AdaLN modulation.
// ---------------------------------------------------------------------------
__device__ __forceinline__ int swz_off(int row, int cb) {
  int line = row >> 1;
  return (line << 7) + (((((row & 1) << 2) | cb) ^ (line & 7)) << 4);
}

__global__ __launch_bounds__(512, 2) void gemm_kv256(
    const bf16* __restrict__ A, const bf16* __restrict__ Bt,
    bf16* __restrict__ Cout, bf16* __restrict__ Cout2,
    const bf16* __restrict__ Aq, const bf16* __restrict__ Bq,
    bf16* __restrict__ qout, const float* __restrict__ shiftp,
    const float* __restrict__ scalep) {
  extern __shared__ char smem[];
  int tid = threadIdx.x;
  int lane = tid & 63, wv = tid >> 6;
  int lr = lane & 15, quad = lane >> 4;
  int bid = blockIdx.x;

  if (bid >= 512) {
    // ---- fused q-projection: 64x64 tile, 8 waves (16x32 out each),
    // 3-buffer counted rotation (1 async16/thread/matrix -> vmcnt(2)) ----
    int q2 = bid - 512;  // 0..255
    int m0q = (q2 >> 4) * 64, n0q = (q2 & 15) * 64;
    int wrq = wv >> 1, wcq = wv & 1;
    int srow = tid >> 3;
    int scb = (tid & 7) ^ (srow & 7);
    size_t ga = (size_t)(m0q + srow) * 1024 + scb * 8;
    size_t gb = (size_t)(n0q + srow) * 1024 + scb * 8;
    int ldsW = wv * 1024;  // wave-uniform byte base (lane*16 implicit)
    auto stq = [&](int step, int buf) {
      int kt = step * 64;
      async16(&Aq[ga + kt], smem + buf * 8192 + ldsW);
      async16(&Bq[gb + kt], smem + 24576 + buf * 8192 + ldsW);
    };
    f32x4 accq[2] = {};
    stq(0, 0);
    stq(1, 1);
    asm volatile("s_waitcnt vmcnt(2)" ::: "memory");
    __builtin_amdgcn_s_barrier();
#pragma unroll 1
    for (int s = 0; s < 16; s++) {
      int cur = s % 3;
      int nxt = (s + 2 < 16) ? s + 2 : 15;  // tail: dead restage
      stq(nxt, (s + 2) % 3);
      const bf16* Ab = (const bf16*)(smem + cur * 8192);
      const bf16* Bb = (const bf16*)(smem + 24576 + cur * 8192);
      for (int kk = 0; kk < 2; kk++) {
        int arow = wrq * 16 + lr;
        bf16x8 afq =
            *(const bf16x8*)&Ab[arow * 64 + ((4 * kk + quad) ^ (arow & 7)) * 8];
        for (int in = 0; in < 2; in++) {
          int brow = wcq * 32 + in * 16 + lr;
          bf16x8 bfq =
              *(const bf16x8*)&Bb[brow * 64 + ((4 * kk + quad) ^ (brow & 7)) * 8];
          accq[in] = __builtin_amdgcn_mfma_f32_16x16x32_bf16(afq, bfq, accq[in],
                                                             0, 0, 0);
        }
      }
      asm volatile("s_waitcnt vmcnt(2)" ::: "memory");
      __builtin_amdgcn_s_barrier();
    }
    // epilogue: AdaLN modulation * attn_scale * log2e, bf16 store
    for (int in = 0; in < 2; in++) {
      int col = n0q + wcq * 32 + in * 16 + lr;
      int hh = col >> 6;
      for (int r = 0; r < 4; r++) {
        int row = m0q + wrq * 16 + quad * 4 + r;
        int bb = row >> 8;
        float sc = scalep[bb * 16 + hh], sh = shiftp[bb * 16 + hh];
        qout[(size_t)row * 1024 + col] =
            (bf16)((accq[in][r] * (1.0f + sc) + sh) * 0.18033688011112042f);
      }
    }
    return;
  }

  // ---- kv path: verified r4 body (BK=64, 2 buffers, 128 KiB LDS) ----
  int wr = wv >> 2, wc = wv & 3;
  int mt = (bid & 7) * 8 + ((bid >> 3) >> 3), nt = (bid >> 3) & 7;
  int m0 = mt * 256, n0 = nt * 256;

  // fragment byte-offsets within a khalf tile
  int offA[8], offB[4];
#pragma unroll
  for (int im = 0; im < 8; im++) offA[im] = swz_off(wr * 128 + im * 16 + lr, quad);
#pragma unroll
  for (int in = 0; in < 4; in++) offB[in] = swz_off(wc * 64 + in * 16 + lr, quad);

  // staging: unit u = s*512+tid holds logical (row, cb) of the khalf tile
  size_t gA[2], gB[2];
#pragma unroll
  for (int s = 0; s < 2; s++) {
    int u = s * 512 + tid;
    int line = u >> 3, inner = (u & 7) ^ (line & 7);
    int row = line * 2 + (inner >> 2), cb = inner & 3;
    gA[s] = (size_t)(m0 + row) * 1024 + cb * 8;
    gB[s] = (size_t)(n0 + row) * 1024 + cb * 8;
  }
  int ldsS0 = wv * 1024, ldsS1 = 8192 + wv * 1024;  // wave-uniform LDS dests

  auto stA = [&](int b, int kh, int k0) {
    char* base = smem + b * 32768 + kh * 16384;
    async16(&A[gA[0] + k0], base + ldsS0);
    async16(&A[gA[1] + k0], base + ldsS1);
  };
  auto stB = [&](int b, int kh, int k0) {
    char* base = smem + 65536 + b * 32768 + kh * 16384;
    async16(&Bt[gB[0] + k0], base + ldsS0);
    async16(&Bt[gB[1] + k0], base + ldsS1);
  };

  f32x4 acc[8][4] = {};

  // prologue: tile0 (kh0,kh1) + tile1 kh0; allow tile1-kh0's 4 loads in flight
  stA(0, 0, 0);  stB(0, 0, 0);
  stA(0, 1, 32); stB(0, 1, 32);
  stA(1, 0, 64); stB(1, 0, 64);
  asm volatile("s_waitcnt vmcnt(4)" ::: "memory");
  __builtin_amdgcn_s_barrier();

#pragma unroll 1
  for (int t = 0; t < 16; t++) {
    int b = t & 1;
    const char* A0 = smem + b * 32768;
    const char* A1 = A0 + 16384;
    const char* B0 = smem + 65536 + b * 32768;
    const char* B1 = B0 + 16384;
    // clamped tails restage identical bytes -> harmless, keeps vmcnt uniform
    int k1 = (t + 1 < 16 ? t + 1 : 15) * 64;
    int k2 = (t + 2 < 16 ? t + 2 : 15) * 64;
    bf16x8 af[4], bfr[4];
    // ---- P1: kh0, mh0 ----
#pragma unroll
    for (int in = 0; in < 4; in++) bfr[in] = *(const bf16x8*)(B0 + offB[in]);
#pragma unroll
    for (int im = 0; im < 4; im++) af[im] = *(const bf16x8*)(A0 + offA[im]);
    stA(b ^ 1, 1, k1 + 32);
    __builtin_amdgcn_s_barrier();
    __builtin_amdgcn_s_setprio(1);
#pragma unroll
    for (int im = 0; im < 4; im++)
#pragma unroll
      for (int in = 0; in < 4; in++)
        acc[im][in] = __builtin_amdgcn_mfma_f32_16x16x32_bf16(
            af[im], bfr[in], acc[im][in], 0, 0, 0);
    __builtin_amdgcn_s_setprio(0);
    __builtin_amdgcn_s_barrier();
    // ---- P2: kh0, mh1 ----
#pragma unroll
    for (int im = 0; im < 4; im++) af[im] = *(const bf16x8*)(A0 + offA[4 + im]);
    stB(b ^ 1, 1, k1 + 32);
    __builtin_amdgcn_s_barrier();
    __builtin_amdgcn_s_setprio(1);
#pragma unroll
    for (int im = 0; im < 4; im++)
#pragma unroll
      for (int in = 0; in < 4; in++)
        acc[4 + im][in] = __builtin_amdgcn_mfma_f32_16x16x32_bf16(
            af[im], bfr[in], acc[4 + im][in], 0, 0, 0);
    __builtin_amdgcn_s_setprio(0);
    __builtin_amdgcn_s_barrier();
    // ---- P3: kh1, mh0 ----
#pragma unroll
    for (int in = 0; in < 4; in++) bfr[in] = *(const bf16x8*)(B1 + offB[in]);
#pragma unroll
    for (int im = 0; im < 4; im++) af[im] = *(const bf16x8*)(A1 + offA[im]);
    stA(b, 0, k2);  // kh0 of this buffer: fully read at P1/P2, freed by P2's barrier
    __builtin_amdgcn_s_barrier();
    __builtin_amdgcn_s_setprio(1);
#pragma unroll
    for (int im = 0; im < 4; im++)
#pragma unroll
      for (int in = 0; in < 4; in++)
        acc[im][in] = __builtin_amdgcn_mfma_f32_16x16x32_bf16(
            af[im], bfr[in], acc[im][in], 0, 0, 0);
    __builtin_amdgcn_s_setprio(0);
    __builtin_amdgcn_s_barrier();
    // ---- P4: kh1, mh1 ----
#pragma unroll
    for (int im = 0; im < 4; im++) af[im] = *(const bf16x8*)(A1 + offA[4 + im]);
    stB(b, 0, k2);
    __builtin_amdgcn_s_barrier();
    __builtin_amdgcn_s_setprio(1);
#pragma unroll
    for (int im = 0; im < 4; im++)
#pragma unroll
      for (int in = 0; in < 4; in++)
        acc[4 + im][in] = __builtin_amdgcn_mfma_f32_16x16x32_bf16(
            af[im], bfr[in], acc[4 + im][in], 0, 0, 0);
    __builtin_amdgcn_s_setprio(0);
    // counted guard BEFORE the tile-end barrier: all but the newest 4 loads
    // (P3+P4 stages) have landed in every wave; barrier publishes cross-wave.
    asm volatile("s_waitcnt vmcnt(4)" ::: "memory");
    __builtin_amdgcn_s_barrier();
  }

  // drain remaining in-flight stages before reusing LDS in the epilogue
  asm volatile("s_waitcnt vmcnt(0)" ::: "memory");
  __builtin_amdgcn_s_barrier();

  if (n0 < 1024) {
    // K half: direct bf16 stores (L2 combines the 16-lane segments)
#pragma unroll
    for (int im = 0; im < 8; im++)
#pragma unroll
      for (int in = 0; in < 4; in++) {
        int col = n0 + wc * 64 + in * 16 + lr;
#pragma unroll
        for (int r = 0; r < 4; r++) {
          int row = m0 + wr * 128 + im * 16 + quad * 4 + r;
          Cout[(size_t)row * 1024 + col] = (bf16)acc[im][in][r];
        }
      }
    return;
  }
  // V half: per-wave LDS transpose (own 8704B region), b128 stores along key
  int b2 = m0 >> 12;
  int key0 = (m0 & 4095) + wr * 128;
  int gc0 = (n0 - 1024) + wc * 64;
  bf16* Tw = (bf16*)(smem + wv * 8704);  // [32 cols][136 keys pitch]
  for (int pass = 0; pass < 2; pass++) {
#pragma unroll
    for (int ii = 0; ii < 2; ii++) {
      int in = pass * 2 + ii;
      int cl = ii * 16 + lr;
#pragma unroll
      for (int im = 0; im < 8; im++) {
        bf16x4 pk;
#pragma unroll
        for (int r = 0; r < 4; r++) pk[r] = (bf16)acc[im][in][r];
        *(bf16x4*)&Tw[cl * 136 + im * 16 + quad * 4] = pk;
      }
    }
    asm volatile("s_waitcnt lgkmcnt(0)" ::: "memory");
#pragma unroll
    for (int j = 0; j < 8; j++) {
      int idx = j * 64 + lane;
      int cl = idx >> 4, k8 = idx & 15;
      uint4 val = *(const uint4*)&Tw[cl * 136 + k8 * 8];
      *(uint4*)&Cout2[((size_t)(b2 * 1024 + gc0 + pass * 32 + cl)) * 4096 +
                      key0 + k8 * 8] = val;
    }
    asm volatile("s_waitcnt lgkmcnt(0)" ::: "memory");
  }
}

// ---------------------------------------------------------------------------
// Small GEMM: 64x64 tile, BK=64, 3-buffer rotation with counted vmcnt.
// (round-3 version; used only for the output projection)
// ---------------------------------------------------------------------------
template <int MODE>
__global__ __launch_bounds__(256) void gemm64(
    const bf16* __restrict__ A, const bf16* __restrict__ Bt,
    void* __restrict__ Cout, int K, int N,
    const float* __restrict__ shiftp, const float* __restrict__ scalep) {
  __shared__ __align__(16) bf16 As[3][64 * 64];
  __shared__ __align__(16) bf16 Bs[3][64 * 64];
  int tid = threadIdx.x;
  int lane = tid & 63, wv = tid >> 6;
  int wr = wv >> 1, wc = wv & 1;
  int quad = lane >> 4, lr = lane & 15;
  int m0 = blockIdx.y * 64, n0 = blockIdx.x * 64;
  f32x4 acc[2][2] = {};

  auto stage = [&](int step, int buf) {
    int kt = step * 64;
    for (int j = 0; j < 2; j++) {
      int idx0 = j * 256 + wv * 64;
      int row = (idx0 >> 3) + (lane >> 3);
      int cb = (lane & 7) ^ (row & 7);
      async16(&A[(size_t)(m0 + row) * K + kt + cb * 8], &As[buf][idx0 * 8]);
      async16(&Bt[(size_t)(n0 + row) * K + kt + cb * 8], &Bs[buf][idx0 * 8]);
    }
  };

  int nsteps = K >> 6;  // 16
  stage(0, 0);
  stage(1, 1);
  asm volatile("s_waitcnt vmcnt(4)" ::: "memory");
  __builtin_amdgcn_s_barrier();

#pragma unroll 1
  for (int s = 0; s < nsteps; s++) {
    int cur = s % 3;
    int nxt = (s + 2 < nsteps) ? s + 2 : nsteps - 1;  // tail: dead restage
    stage(nxt, (s + 2) % 3);
    for (int kk = 0; kk < 2; kk++) {
      bf16x8 af[2], bfr[2];
      for (int im = 0; im < 2; im++) {
        int row = wr * 32 + im * 16 + lr;
        af[im] =
            *(const bf16x8*)&As[cur][row * 64 + ((quad + 4 * kk) ^ (row & 7)) * 8];
      }
      for (int in = 0; in < 2; in++) {
        int row = wc * 32 + in * 16 + lr;
        bfr[in] =
            *(const bf16x8*)&Bs[cur][row * 64 + ((quad + 4 * kk) ^ (row & 7)) * 8];
      }
      for (int im = 0; im < 2; im++)
        for (int in = 0; in < 2; in++)
          acc[im][in] = __builtin_amdgcn_mfma_f32_16x16x32_bf16(
              af[im], bfr[in], acc[im][in], 0, 0, 0);
    }
    asm volatile("s_waitcnt vmcnt(4)" ::: "memory");
    __builtin_amdgcn_s_barrier();
  }

  for (int im = 0; im < 2; im++)
    for (int in = 0; in < 2; in++) {
      int col = n0 + wc * 32 + in * 16 + lr;
      for (int r = 0; r < 4; r++) {
        int row = m0 + wr * 32 + im * 16 + quad * 4 + r;
        float v = acc[im][in][r];
        if (MODE == 1) {
          int bb = row >> 8, hh = col >> 6;
          float sc = scalep[bb * 16 + hh], sh = shiftp[bb * 16 + hh];
          ((bf16*)Cout)[(size_t)row * N + col] =
              (bf16)((v * (1.0f + sc) + sh) * 0.18033688011112042f);
        } else {
          ((float*)Cout)[(size_t)row * N + col] = v;
        }
      }
    }
}

// ---------------------------------------------------------------------------
// Flash attention: merged q-tiles + exact defer-rescale. (round-5, kept)
// ---------------------------------------------------------------------------
__global__ __launch_bounds__(512) void attn_kernel(const bf16* __restrict__ q,
                                                   const bf16* __restrict__ kb,
                                                   const bf16* __restrict__ vt,
                                                   bf16* __restrict__ opb,
                                                   float* __restrict__ lseb) {
  int b = blockIdx.z, h = blockIdx.y;
  int sp = blockIdx.x;
  int tid = threadIdx.x, lane = tid & 63, wv = tid >> 6;
  int quad = lane >> 4, lr = lane & 15;
  __shared__ __align__(16) bf16 Ks[2][64 * 64];
  __shared__ __align__(16) bf16 Vs[2][64 * 64];   // [dh][key]
  __shared__ __align__(16) bf16 QP[256 * 64];     // 256 Q rows; P overlays own rows

  // stage all 256 Q rows (4 async16/thread, 8 waves x 8 rows per pass)
  const bf16* qg = q + (size_t)(b * N2) * INNER + h * DH;
  for (int j = 0; j < 4; j++) {
    int r0 = j * 64 + wv * 8;
    int r = r0 + (lane >> 3);
    async16(&qg[(size_t)r * INNER + ((lane & 7) ^ (r & 7)) * 8], &QP[r0 * 64]);
  }
  __syncthreads();
  bf16x8 aQ[2][2];
  for (int g = 0; g < 2; g++) {
    int row = wv * 32 + g * 16 + lr;
    for (int kk = 0; kk < 2; kk++)
      aQ[g][kk] = *(const bf16x8*)&QP[row * 64 + ((quad + 4 * kk) ^ (row & 7)) * 8];
  }
  float m_s[2] = {-1e30f, -1e30f}, l_s[2] = {0.0f, 0.0f};
  f32x4 oacc[2][4] = {};

  const bf16* kg = kb + (size_t)(b * N1) * 1024 + h * DH;
  const bf16* vg = vt + (size_t)((b * HEADS + h) * DH) * N1;
  bf16* Ps = QP + wv * 2048;  // wave's own 32 Q rows (Q already in regs)

  auto stageKV = [&](int t, int buf) {
    int key0 = sp * KEYS_PER_SPLIT + t * 64;
    int r0 = wv * 8;                 // 8 waves x 8 rows = 64 rows in one pass
    int r = r0 + (lane >> 3);
    int cs = ((lane & 7) ^ (r & 7)) * 8;
    async16(&kg[(size_t)(key0 + r) * 1024 + cs], &Ks[buf][r0 * 64]);
    async16(&vg[(size_t)r * N1 + key0 + cs], &Vs[buf][r0 * 64]);
  };

  // prologue: tile 0 into buf 0
  stageKV(0, 0);
  asm volatile("s_waitcnt vmcnt(0)" ::: "memory");
  __builtin_amdgcn_s_barrier();

  for (int t = 0; t < KEYS_PER_SPLIT / 64; t++) {
    int cur = t & 1;
    // hoist K/V fragments once, reuse across both q-groups
    bf16x8 ak[2][4], bv[2][4];
    for (int kk = 0; kk < 2; kk++)
      for (int nt = 0; nt < 4; nt++) {
        int row = nt * 16 + lr;
        ak[kk][nt] =
            *(const bf16x8*)&Ks[cur][row * 64 + ((quad + 4 * kk) ^ (row & 7)) * 8];
        bv[kk][nt] =
            *(const bf16x8*)&Vs[cur][row * 64 + ((quad + 4 * kk) ^ (row & 7)) * 8];
      }
    if (t + 1 < KEYS_PER_SPLIT / 64) stageKV(t + 1, cur ^ 1);

    for (int g = 0; g < 2; g++) {
      f32x4 s[4] = {};
      for (int kk = 0; kk < 2; kk++)
        for (int nt = 0; nt < 4; nt++)
          s[nt] = __builtin_amdgcn_mfma_f32_16x16x32_bf16(ak[kk][nt], aQ[g][kk],
                                                          s[nt], 0, 0, 0);
      // per-lane softmax for query = lr (16 keys in regs, reduce across quads)
      float mx = s[0][0];
      for (int nt = 0; nt < 4; nt++)
        for (int r = 0; r < 4; r++) mx = fmaxf(mx, s[nt][r]);
      mx = fmaxf(mx, __shfl_xor(mx, 16, 64));
      mx = fmaxf(mx, __shfl_xor(mx, 32, 64));
      float mo = m_s[g];
      float mn = fmaxf(mo, mx);
      float al = exp2f(mo - mn);
      float p[4][4], sum = 0.0f;
      for (int nt = 0; nt < 4; nt++)
        for (int r = 0; r < 4; r++) {
          p[nt][r] = exp2f(s[nt][r] - mn);
          sum += p[nt][r];
        }
      sum += __shfl_xor(sum, 16, 64);
      sum += __shfl_xor(sum, 32, 64);
      l_s[g] = l_s[g] * al + sum;
      m_s[g] = mn;

      // packed P writes: P[query=lr][key=16nt+4quad+r]
      for (int nt = 0; nt < 4; nt++) {
        bf16x4 pk;
        for (int r = 0; r < 4; r++) pk[r] = (bf16)p[nt][r];
        *(bf16x4*)&Ps[lr * 64 + ((2 * nt + (quad >> 1)) ^ (lr & 7)) * 8 +
                      (quad & 1) * 4] = pk;
      }

      // rescale O accumulator only when some lane's max grew (al != 1.0);
      // otherwise al == 1.0 exactly and the rescale is a no-op.
      if (__any(mn > mo)) {
        for (int r = 0; r < 4; r++) {
          float a = __shfl(al, quad * 4 + r, 16);
          for (int in = 0; in < 4; in++) oacc[g][in][r] *= a;
        }
      }

      bf16x8 aP[2];
      for (int kk = 0; kk < 2; kk++)
        aP[kk] = *(const bf16x8*)&Ps[lr * 64 + ((4 * kk + quad) ^ (lr & 7)) * 8];
      for (int kk = 0; kk < 2; kk++)
        for (int in = 0; in < 4; in++)
          oacc[g][in] = __builtin_amdgcn_mfma_f32_16x16x32_bf16(
              aP[kk], bv[kk][in], oacc[g][in], 0, 0, 0);
    }
    // stage issued at tile start has landed (whole compute passed): free wait
    asm volatile("s_waitcnt vmcnt(0)" ::: "memory");
    __builtin_amdgcn_s_barrier();
  }

  // epilogue: normalized bf16 partials + lse
  bf16* ob = opb + (size_t)sp * SPLIT_ELEMS;
  size_t rbase = (size_t)(b * HEADS + h) * N2;
  for (int g = 0; g < 2; g++) {
    for (int r = 0; r < 4; r++) {
      float lrow = __shfl(l_s[g], quad * 4 + r, 16);
      float inv = 1.0f / lrow;
      int qq = wv * 32 + g * 16 + quad * 4 + r;
      for (int in = 0; in < 4; in++)
        ob[(rbase + qq) * 64 + in * 16 + lr] = (bf16)(oacc[g][in][r] * inv);
    }
    if (quad == 0) {
      int qq = wv * 32 + g * 16 + lr;
      lseb[(size_t)sp * ROWS_TOTAL + rbase + qq] = m_s[g] + __log2f(l_s[g]);
    }
  }
}

// ---------------------------------------------------------------------------
// Combine (round-5 fixed version, kept): one thread per 8-elem d-chunk.
// ---------------------------------------------------------------------------
__global__ __launch_bounds__(256) void combine_kernel(const bf16* __restrict__ opb,
                                                      const float* __restrict__ lseb,
                                                      bf16* __restrict__ out) {
  int gid = blockIdx.x * 256 + threadIdx.x;  // 131072 threads total
  int dc = (gid & 7) * 8;
  int rq = gid >> 3;  // (b*16+h)*256 + q, in [0, 16384)
  int qq = rq & 255, bh = rq >> 8;
  int h = bh & 15, b = bh >> 4;
  float ls[ASPLIT];
  for (int s = 0; s < ASPLIT; s++) ls[s] = lseb[(size_t)s * ROWS_TOTAL + rq];
  float M = fmaxf(fmaxf(ls[0], ls[1]), fmaxf(ls[2], ls[3]));
  float L = 0.0f, w[ASPLIT];
  for (int s = 0; s < ASPLIT; s++) {
    w[s] = exp2f(ls[s] - M);
    L += w[s];
  }
  float inv = 1.0f / L;
  float o[8] = {};
  for (int s = 0; s < ASPLIT; s++) {
    bf16x8 v = *(const bf16x8*)&opb[(size_t)s * SPLIT_ELEMS + (size_t)rq * 64 + dc];
    for (int j = 0; j < 8; j++) o[j] += w[s] * (float)v[j];
  }
  bf16x8 ov;
  for (int j = 0; j < 8; j++) ov[j] = (bf16)(o[j] * inv);
  *(bf16x8*)&out[((size_t)(b * N2 + qq)) * INNER + h * DH + dc] = ov;
}

// ---------------------------------------------------------------------------
extern "C" void kernel_launch(void* const* d_in, const int* in_sizes, int n_in,
                              void* d_out, int out_size, void* d_ws,
                              size_t ws_size, hipStream_t stream) {
  const float* x       = (const float*)d_in[0];
  const float* latents = (const float*)d_in[1];
  const float* shift   = (const float*)d_in[2];
  const float* scale   = (const float*)d_in[3];
  const float* ln1w    = (const float*)d_in[4];
  const float* ln1b    = (const float*)d_in[5];
  const float* ln2w    = (const float*)d_in[6];
  const float* ln2b    = (const float*)d_in[7];
  const float* Wq      = (const float*)d_in[8];
  const float* Wkv     = (const float*)d_in[9];
  const float* Wout    = (const float*)d_in[10];

  char* ws = (char*)d_ws;
  bf16*  xn    = (bf16*)(ws);                // 32MiB; dead after gemm_kv
  bf16*  opb   = (bf16*)(ws);                //   overlay: 4 bf16 splits
  bf16*  lnl   = (bf16*)(ws + 33554432);     // 2MB; dead after q gemm
  float* lseb  = (float*)(ws + 33554432);    //   overlay: lse 256KB
  bf16*  qb    = (bf16*)(ws + 35651584);     // 2MB
  bf16*  kb    = (bf16*)(ws + 37748736);     // 32MiB (K half)
  bf16*  vtb   = (bf16*)(ws + 104857600);    // 32MiB (V^T)
  bf16*  aob   = (bf16*)(ws + 138412032);    // 2MB
  bf16*  WqT   = (bf16*)(ws + 140509184);    // 2MB
  bf16*  WkvT  = (bf16*)(ws + 142606336);    // 4MB
  bf16*  WoutT = (bf16*)(ws + 146800640);    // 2MB

  static bool attr_done = false;
  if (!attr_done) {
    hipFuncSetAttribute(reinterpret_cast<const void*>(gemm_kv256),
                        hipFuncAttributeMaxDynamicSharedMemorySize, 131072);
    attr_done = true;
  }

  prep<<<8448, 256, 0, stream>>>(Wq, Wkv, Wout, WqT, WkvT, WoutT, x, latents,
                                 ln1w, ln1b, ln2w, ln2b, xn, lnl);
  gemm_kv256<<<dim3(768), dim3(512), 131072, stream>>>(
      xn, WkvT, kb, vtb, lnl, WqT, qb, shift, scale);
  attn_kernel<<<dim3(ASPLIT, 16, 4), 512, 0, stream>>>(qb, kb, vtb, opb,
                                                       lseb);
  combine_kernel<<<512, 256, 0, stream>>>(opb, lseb, aob);
  gemm64<2><<<dim3(16, 16), 256, 0, stream>>>(aob, WoutT, d_out, 1024, 1024,
                                              nullptr, nullptr);
}